// Round 7
// baseline (25.002 us; speedup 1.0000x reference)
//
#include <hip/hip_runtime.h>

typedef short short8 __attribute__((ext_vector_type(8)));
typedef float f32x4 __attribute__((ext_vector_type(4)));

static __device__ __forceinline__ unsigned short f2bf(float f) {
    unsigned u = __builtin_bit_cast(unsigned, f);
    u += 0x7FFFu + ((u >> 16) & 1u);   // RNE
    return (unsigned short)(u >> 16);
}
static __device__ __forceinline__ float bf2f(unsigned short h) {
    unsigned u = ((unsigned)h) << 16;
    return __builtin_bit_cast(float, u);
}
// 2x f32 -> packed bf16 (RNE) in one VALU op
static __device__ __forceinline__ unsigned cvtpk_bf16(float lo, float hi) {
    unsigned r;
    asm("v_cvt_pk_bf16_f32 %0, %1, %2" : "=v"(r) : "v"(lo), "v"(hi));
    return r;
}

// ws layout (fragment-major, verified rounds 3/4/6):
//   [0,128K)    Btg  bf16: element (n,k) of Wp^T at
//               idx = (k>>5)*8192 + (n>>4)*512 + (n&15)*32 + (k&31)
//   [128K,256K) injT bf16 per b: element (col,n) at
//               idx = b*8192 + (col>>4)*512 + (col&15)*32 + n   (n=16..31 zero)
#define OFF_INJT (128 * 1024)

// Prep (unchanged from round 6): blocks 0..15 -> Wp^T tiles; 16..47 -> inj MFMA
__global__ __launch_bounds__(256)
void prep_kernel(const float* __restrict__ embs,
                 const float* __restrict__ Wp,
                 const float* __restrict__ We,
                 unsigned short* __restrict__ Btg,
                 unsigned short* __restrict__ injT) {
    __shared__ float sh[64 * 65];
    __shared__ unsigned short Ebf[16 * 256];  // bf16, rows XOR-swizzled

    const int bid = blockIdx.x, t = threadIdx.x;

    if (bid < 16) {
        const int kt = (bid >> 2) * 64, n0 = (bid & 3) * 64;
        #pragma unroll
        for (int it = 0; it < 16; ++it) {
            int u = t + it * 256;
            int kl = u >> 6, nl = u & 63;
            sh[kl * 65 + nl] = Wp[(kt + kl) * 256 + n0 + nl];
        }
        __syncthreads();
        #pragma unroll
        for (int it = 0; it < 4; ++it) {
            int v = t + it * 256;
            int nl = v >> 4, kg = v & 15;   // k = kt + kg*4 + c
            ushort4 o;
            o.x = f2bf(sh[(kg * 4 + 0) * 65 + nl]);
            o.y = f2bf(sh[(kg * 4 + 1) * 65 + nl]);
            o.z = f2bf(sh[(kg * 4 + 2) * 65 + nl]);
            o.w = f2bf(sh[(kg * 4 + 3) * 65 + nl]);
            int ks = (kt >> 5) + (kg >> 3);
            int n16 = (n0 >> 4) + (nl >> 4);
            int idx = ks * 8192 + n16 * 512 + (nl & 15) * 32 + ((kg >> 1) & 3) * 8 + (kg & 1) * 4;
            *reinterpret_cast<ushort4*>(&Btg[idx]) = o;
        }
    } else {
        const int ib = bid - 16;
        const int b = ib >> 2, oq = ib & 3;

        if (t < 128) {
            const int c0 = t * 2;
            #pragma unroll
            for (int r = 0; r < 15; ++r) {
                float2 v = *reinterpret_cast<const float2*>(embs + (size_t)(b * 15 + r) * 256 + c0);
                unsigned pk = (unsigned)f2bf(v.x) | ((unsigned)f2bf(v.y) << 16);
                *reinterpret_cast<unsigned*>(reinterpret_cast<char*>(Ebf)
                    + r * 512 + ((c0 * 2) ^ ((r & 7) << 4))) = pk;
            }
        }
        __syncthreads();
        if (t < 128) {   // mean row 15
            const int c0 = t * 2;
            float s0 = 0.f, s1 = 0.f;
            #pragma unroll
            for (int r = 0; r < 15; ++r) {
                unsigned pk = *reinterpret_cast<const unsigned*>(reinterpret_cast<char*>(Ebf)
                    + r * 512 + ((c0 * 2) ^ ((r & 7) << 4)));
                s0 += bf2f((unsigned short)(pk & 0xffffu));
                s1 += bf2f((unsigned short)(pk >> 16));
            }
            unsigned pk = (unsigned)f2bf(s0 * (1.0f / 15.0f))
                        | ((unsigned)f2bf(s1 * (1.0f / 15.0f)) << 16);
            *reinterpret_cast<unsigned*>(reinterpret_cast<char*>(Ebf)
                + 15 * 512 + ((c0 * 2) ^ ((7) << 4))) = pk;
        }
        __syncthreads();

        const int wv = t >> 6, lane = t & 63, lhi = lane >> 4, llo = lane & 15;
        const int oc = oq * 64 + wv * 16 + llo;

        f32x4 acc = (f32x4){0.f, 0.f, 0.f, 0.f};
        #pragma unroll
        for (int ks = 0; ks < 8; ++ks) {
            const short8 afr = *reinterpret_cast<const short8*>(
                reinterpret_cast<const char*>(Ebf)
                + llo * 512 + ((ks * 64 + lhi * 16) ^ ((llo & 7) << 4)));
            short8 bfr;
            #pragma unroll
            for (int r = 0; r < 8; ++r)
                bfr[r] = (short)f2bf(We[(size_t)(ks * 32 + lhi * 8 + r) * 256 + oc]);
            acc = __builtin_amdgcn_mfma_f32_16x16x32_bf16(afr, bfr, acc, 0, 0, 0);
        }
        ushort4 o4;
        o4.x = f2bf(acc[0]); o4.y = f2bf(acc[1]);
        o4.z = f2bf(acc[2]); o4.w = f2bf(acc[3]);
        unsigned short* dst = injT + (size_t)b * 8192 + (oq * 4 + wv) * 512 + llo * 32;
        *reinterpret_cast<ushort4*>(dst + lhi * 4) = o4;
        ushort4 z = {0, 0, 0, 0};
        *reinterpret_cast<ushort4*>(dst + 16 + lhi * 4) = z;
    }
}

// Fused v3: 512 threads (8 waves) per 16-pixel tile; wave owns 2 n16 column
// groups. Zero LDS, zero barriers; per-thread mask with rc folded into the
// mask MFMA fragment (bf16).
__global__ __launch_bounds__(512, 4)
void fused_kernel(const float* __restrict__ patches,
                  const int* __restrict__ locations,
                  const unsigned short* __restrict__ Btg,
                  const unsigned short* __restrict__ injT,
                  float* __restrict__ out) {
    const int bid = blockIdx.x, t = threadIdx.x;
    const int b = bid >> 6, p0 = (bid & 63) * 16;
    const int wv = t >> 6, lane = t & 63, lhi = lane >> 4, llo = lane & 15;

    // per-thread mask + 1/cnt for pixel p0+llo (locations loads are
    // block-uniform -> scalar s_load; box tests ~8 VALU each)
    const int p = p0 + llo, h = p >> 5, w = p & 31;
    const int* loc = locations + b * 60;
    unsigned m = 1u << 15;  // full-image box always contains
    #pragma unroll
    for (int nb = 0; nb < 15; ++nb) {
        int y0 = loc[nb * 4 + 0] & ~1;
        int x0 = loc[nb * 4 + 1] & ~1;
        int y1 = (loc[nb * 4 + 2] & ~1) + 2;
        int x1 = (loc[nb * 4 + 3] & ~1) + 2;
        if (h >= y0 && h < y1 && w >= x0 && w < x1) m |= 1u << nb;
    }
    const unsigned short rcb = f2bf(1.0f / (float)__popc(m));
    short8 mfrag;
    #pragma unroll
    for (int r = 0; r < 8; ++r) {
        int k = lhi * 8 + r;
        mfrag[r] = (k < 16 && ((m >> k) & 1u)) ? (short)rcb : (short)0;
    }

    // masked-mean epilogue term first: its L2 loads + 2 MFMA hide under the GEMM
    f32x4 accE[2];
    {
        const short8 jf0 = *reinterpret_cast<const short8*>(
            injT + (size_t)b * 8192 + (wv * 2 + 0) * 512 + llo * 32 + lhi * 8);
        const short8 jf1 = *reinterpret_cast<const short8*>(
            injT + (size_t)b * 8192 + (wv * 2 + 1) * 512 + llo * 32 + lhi * 8);
        accE[0] = __builtin_amdgcn_mfma_f32_16x16x32_bf16(
            mfrag, jf0, (f32x4){0.f, 0.f, 0.f, 0.f}, 0, 0, 0);
        accE[1] = __builtin_amdgcn_mfma_f32_16x16x32_bf16(
            mfrag, jf1, (f32x4){0.f, 0.f, 0.f, 0.f}, 0, 0, 0);
    }

    // A fragments from HBM, packed with v_cvt_pk_bf16_f32 (4 ops / fragment)
    const float* arow = patches + (size_t)(b * 1024 + p0 + llo) * 256;
    short8 af[8];
    #pragma unroll
    for (int ks = 0; ks < 8; ++ks) {
        float4 f0 = *reinterpret_cast<const float4*>(arow + ks * 32 + lhi * 8);
        float4 f1 = *reinterpret_cast<const float4*>(arow + ks * 32 + lhi * 8 + 4);
        union { short8 s; unsigned u[4]; } A;
        A.u[0] = cvtpk_bf16(f0.x, f0.y);
        A.u[1] = cvtpk_bf16(f0.z, f0.w);
        A.u[2] = cvtpk_bf16(f1.x, f1.y);
        A.u[3] = cvtpk_bf16(f1.z, f1.w);
        af[ks] = A.s;
    }

    // proj GEMM: B fragment loads 1KB contiguous per wave, L2-resident
    f32x4 acc[2];
    acc[0] = (f32x4){0.f, 0.f, 0.f, 0.f};
    acc[1] = (f32x4){0.f, 0.f, 0.f, 0.f};
    #pragma unroll
    for (int ks = 0; ks < 8; ++ks) {
        #pragma unroll
        for (int nt = 0; nt < 2; ++nt) {
            const short8 bf = *reinterpret_cast<const short8*>(
                Btg + ks * 8192 + (wv * 2 + nt) * 512 + llo * 32 + lhi * 8);
            acc[nt] = __builtin_amdgcn_mfma_f32_16x16x32_bf16(af[ks], bf, acc[nt], 0, 0, 0);
        }
    }

    float* ob = out + ((size_t)b * 1024 + p0) * 256;
    #pragma unroll
    for (int nt = 0; nt < 2; ++nt)
        #pragma unroll
        for (int j = 0; j < 4; ++j)
            ob[(lhi * 4 + j) * 256 + (wv * 2 + nt) * 16 + llo] = acc[nt][j] + accE[nt][j];
}

extern "C" void kernel_launch(void* const* d_in, const int* in_sizes, int n_in,
                              void* d_out, int out_size, void* d_ws, size_t ws_size,
                              hipStream_t stream) {
    const float* patches = (const float*)d_in[0];
    const float* embs    = (const float*)d_in[1];
    const int*   locs    = (const int*)d_in[2];
    const float* Wp      = (const float*)d_in[3];
    const float* We      = (const float*)d_in[4];
    float* out = (float*)d_out;

    unsigned short* Btg  = (unsigned short*)d_ws;
    unsigned short* injT = (unsigned short*)((char*)d_ws + OFF_INJT);

    prep_kernel<<<48, 256, 0, stream>>>(embs, Wp, We, Btg, injT);
    fused_kernel<<<512, 512, 0, stream>>>(patches, locs, Btg, injT, out);
}

// Round 8
// 20.484 us; speedup vs baseline: 1.2206x; 1.2206x over previous
//
#include <hip/hip_runtime.h>

typedef short short8 __attribute__((ext_vector_type(8)));
typedef float f32x4 __attribute__((ext_vector_type(4)));

static __device__ __forceinline__ unsigned short f2bf(float f) {
    unsigned u = __builtin_bit_cast(unsigned, f);
    u += 0x7FFFu + ((u >> 16) & 1u);   // RNE
    return (unsigned short)(u >> 16);
}
static __device__ __forceinline__ float bf2f(unsigned short h) {
    unsigned u = ((unsigned)h) << 16;
    return __builtin_bit_cast(float, u);
}

// ws layout (fragment-major, verified rounds 3/4/6):
//   [0,128K)    Btg  bf16: element (n,k) of Wp^T at
//               idx = (k>>5)*8192 + (n>>4)*512 + (n&15)*32 + (k&31)
//   [128K,256K) injT bf16 per b: element (col,n) at
//               idx = b*8192 + (col>>4)*512 + (col&15)*32 + n   (n=16..31 zero)
#define OFF_INJT (128 * 1024)

// Prep (unchanged from round 6): blocks 0..15 -> Wp^T tiles; 16..47 -> inj MFMA
__global__ __launch_bounds__(256)
void prep_kernel(const float* __restrict__ embs,
                 const float* __restrict__ Wp,
                 const float* __restrict__ We,
                 unsigned short* __restrict__ Btg,
                 unsigned short* __restrict__ injT) {
    __shared__ float sh[64 * 65];
    __shared__ unsigned short Ebf[16 * 256];  // bf16, rows XOR-swizzled

    const int bid = blockIdx.x, t = threadIdx.x;

    if (bid < 16) {
        const int kt = (bid >> 2) * 64, n0 = (bid & 3) * 64;
        #pragma unroll
        for (int it = 0; it < 16; ++it) {
            int u = t + it * 256;
            int kl = u >> 6, nl = u & 63;
            sh[kl * 65 + nl] = Wp[(kt + kl) * 256 + n0 + nl];
        }
        __syncthreads();
        #pragma unroll
        for (int it = 0; it < 4; ++it) {
            int v = t + it * 256;
            int nl = v >> 4, kg = v & 15;   // k = kt + kg*4 + c
            ushort4 o;
            o.x = f2bf(sh[(kg * 4 + 0) * 65 + nl]);
            o.y = f2bf(sh[(kg * 4 + 1) * 65 + nl]);
            o.z = f2bf(sh[(kg * 4 + 2) * 65 + nl]);
            o.w = f2bf(sh[(kg * 4 + 3) * 65 + nl]);
            int ks = (kt >> 5) + (kg >> 3);
            int n16 = (n0 >> 4) + (nl >> 4);
            int idx = ks * 8192 + n16 * 512 + (nl & 15) * 32 + ((kg >> 1) & 3) * 8 + (kg & 1) * 4;
            *reinterpret_cast<ushort4*>(&Btg[idx]) = o;
        }
    } else {
        const int ib = bid - 16;
        const int b = ib >> 2, oq = ib & 3;

        if (t < 128) {
            const int c0 = t * 2;
            #pragma unroll
            for (int r = 0; r < 15; ++r) {
                float2 v = *reinterpret_cast<const float2*>(embs + (size_t)(b * 15 + r) * 256 + c0);
                unsigned pk = (unsigned)f2bf(v.x) | ((unsigned)f2bf(v.y) << 16);
                *reinterpret_cast<unsigned*>(reinterpret_cast<char*>(Ebf)
                    + r * 512 + ((c0 * 2) ^ ((r & 7) << 4))) = pk;
            }
        }
        __syncthreads();
        if (t < 128) {   // mean row 15
            const int c0 = t * 2;
            float s0 = 0.f, s1 = 0.f;
            #pragma unroll
            for (int r = 0; r < 15; ++r) {
                unsigned pk = *reinterpret_cast<const unsigned*>(reinterpret_cast<char*>(Ebf)
                    + r * 512 + ((c0 * 2) ^ ((r & 7) << 4)));
                s0 += bf2f((unsigned short)(pk & 0xffffu));
                s1 += bf2f((unsigned short)(pk >> 16));
            }
            unsigned pk = (unsigned)f2bf(s0 * (1.0f / 15.0f))
                        | ((unsigned)f2bf(s1 * (1.0f / 15.0f)) << 16);
            *reinterpret_cast<unsigned*>(reinterpret_cast<char*>(Ebf)
                + 15 * 512 + ((c0 * 2) ^ ((7) << 4))) = pk;
        }
        __syncthreads();

        const int wv = t >> 6, lane = t & 63, lhi = lane >> 4, llo = lane & 15;
        const int oc = oq * 64 + wv * 16 + llo;

        f32x4 acc = (f32x4){0.f, 0.f, 0.f, 0.f};
        #pragma unroll
        for (int ks = 0; ks < 8; ++ks) {
            const short8 afr = *reinterpret_cast<const short8*>(
                reinterpret_cast<const char*>(Ebf)
                + llo * 512 + ((ks * 64 + lhi * 16) ^ ((llo & 7) << 4)));
            short8 bfr;
            #pragma unroll
            for (int r = 0; r < 8; ++r)
                bfr[r] = (short)f2bf(We[(size_t)(ks * 32 + lhi * 8 + r) * 256 + oc]);
            acc = __builtin_amdgcn_mfma_f32_16x16x32_bf16(afr, bfr, acc, 0, 0, 0);
        }
        ushort4 o4;
        o4.x = f2bf(acc[0]); o4.y = f2bf(acc[1]);
        o4.z = f2bf(acc[2]); o4.w = f2bf(acc[3]);
        unsigned short* dst = injT + (size_t)b * 8192 + (oq * 4 + wv) * 512 + llo * 32;
        *reinterpret_cast<ushort4*>(dst + lhi * 4) = o4;
        ushort4 z = {0, 0, 0, 0};
        *reinterpret_cast<ushort4*>(dst + 16 + lhi * 4) = z;
    }
}

// Fused v4: R6 structure (256 threads, 4 waves, 16-pixel tile, 512 blocks) but
// ZERO LDS and ZERO barriers: per-thread mask with 1/cnt folded (bf16) into the
// mask MFMA fragment. Scalar f2bf pack (compiler-scheduled). A-loads issued
// first; mask + epilogue MFMAs hide under their latency.
__global__ __launch_bounds__(256)
void fused_kernel(const float* __restrict__ patches,
                  const int* __restrict__ locations,
                  const unsigned short* __restrict__ Btg,
                  const unsigned short* __restrict__ injT,
                  float* __restrict__ out) {
    const int bid = blockIdx.x, t = threadIdx.x;
    const int b = bid >> 6, p0 = (bid & 63) * 16;
    const int wv = t >> 6, lane = t & 63, lhi = lane >> 4, llo = lane & 15;

    // ---- issue A-tile loads first (HBM, longest latency) ----
    const float* arow = patches + (size_t)(b * 1024 + p0 + llo) * 256;
    float4 a0[8], a1[8];
    #pragma unroll
    for (int ks = 0; ks < 8; ++ks) {
        a0[ks] = *reinterpret_cast<const float4*>(arow + ks * 32 + lhi * 8);
        a1[ks] = *reinterpret_cast<const float4*>(arow + ks * 32 + lhi * 8 + 4);
    }

    // ---- per-thread mask + 1/cnt for pixel p0+llo (locs loads block-uniform) ----
    const int p = p0 + llo, h = p >> 5, w = p & 31;
    const int* loc = locations + b * 60;
    unsigned m = 1u << 15;  // full-image box always contains
    #pragma unroll
    for (int nb = 0; nb < 15; ++nb) {
        int y0 = loc[nb * 4 + 0] & ~1;
        int x0 = loc[nb * 4 + 1] & ~1;
        int y1 = (loc[nb * 4 + 2] & ~1) + 2;
        int x1 = (loc[nb * 4 + 3] & ~1) + 2;
        if (h >= y0 && h < y1 && w >= x0 && w < x1) m |= 1u << nb;
    }
    const unsigned short rcb = f2bf(1.0f / (float)__popc(m));
    short8 mfrag;
    #pragma unroll
    for (int r = 0; r < 8; ++r) {
        int k = lhi * 8 + r;
        mfrag[r] = (k < 16 && ((m >> k) & 1u)) ? (short)rcb : (short)0;
    }

    // ---- epilogue term (L2 loads + 4 MFMA, hides under A-load latency) ----
    f32x4 accE[4];
    #pragma unroll
    for (int nt = 0; nt < 4; ++nt) {
        const short8 jf = *reinterpret_cast<const short8*>(
            injT + (size_t)b * 8192 + (wv * 4 + nt) * 512 + llo * 32 + lhi * 8);
        accE[nt] = __builtin_amdgcn_mfma_f32_16x16x32_bf16(
            mfrag, jf, (f32x4){0.f, 0.f, 0.f, 0.f}, 0, 0, 0);
    }

    // ---- pack A (scalar f2bf; compiler fuses/schedules) ----
    short8 af[8];
    #pragma unroll
    for (int ks = 0; ks < 8; ++ks) {
        short8 a;
        a[0] = (short)f2bf(a0[ks].x); a[1] = (short)f2bf(a0[ks].y);
        a[2] = (short)f2bf(a0[ks].z); a[3] = (short)f2bf(a0[ks].w);
        a[4] = (short)f2bf(a1[ks].x); a[5] = (short)f2bf(a1[ks].y);
        a[6] = (short)f2bf(a1[ks].z); a[7] = (short)f2bf(a1[ks].w);
        af[ks] = a;
    }

    // ---- proj GEMM: B fragment loads 1KB contiguous per wave (L2-resident) ----
    f32x4 acc[4];
    #pragma unroll
    for (int nt = 0; nt < 4; ++nt) acc[nt] = (f32x4){0.f, 0.f, 0.f, 0.f};
    #pragma unroll
    for (int ks = 0; ks < 8; ++ks) {
        #pragma unroll
        for (int nt = 0; nt < 4; ++nt) {
            const short8 bf = *reinterpret_cast<const short8*>(
                Btg + ks * 8192 + (wv * 4 + nt) * 512 + llo * 32 + lhi * 8);
            acc[nt] = __builtin_amdgcn_mfma_f32_16x16x32_bf16(af[ks], bf, acc[nt], 0, 0, 0);
        }
    }

    float* ob = out + ((size_t)b * 1024 + p0) * 256;
    #pragma unroll
    for (int nt = 0; nt < 4; ++nt)
        #pragma unroll
        for (int j = 0; j < 4; ++j)
            ob[(lhi * 4 + j) * 256 + wv * 64 + nt * 16 + llo] = acc[nt][j] + accE[nt][j];
}

extern "C" void kernel_launch(void* const* d_in, const int* in_sizes, int n_in,
                              void* d_out, int out_size, void* d_ws, size_t ws_size,
                              hipStream_t stream) {
    const float* patches = (const float*)d_in[0];
    const float* embs    = (const float*)d_in[1];
    const int*   locs    = (const int*)d_in[2];
    const float* Wp      = (const float*)d_in[3];
    const float* We      = (const float*)d_in[4];
    float* out = (float*)d_out;

    unsigned short* Btg  = (unsigned short*)d_ws;
    unsigned short* injT = (unsigned short*)((char*)d_ws + OFF_INJT);

    prep_kernel<<<48, 256, 0, stream>>>(embs, Wp, We, Btg, injT);
    fused_kernel<<<512, 256, 0, stream>>>(patches, locs, Btg, injT, out);
}

// Round 9
// 17.136 us; speedup vs baseline: 1.4591x; 1.1954x over previous
//
#include <hip/hip_runtime.h>

typedef short short8 __attribute__((ext_vector_type(8)));
typedef float f32x4 __attribute__((ext_vector_type(4)));

static __device__ __forceinline__ unsigned short f2bf(float f) {
    unsigned u = __builtin_bit_cast(unsigned, f);
    u += 0x7FFFu + ((u >> 16) & 1u);   // RNE
    return (unsigned short)(u >> 16);
}

// Single kernel, single launch. Block = (b, 64-pixel tile, 64-col tile),
// 4 waves; wave owns 16 cols x 64 pixels. All prep recomputed per block:
//  - A (patches) staged once -> bf16 swizzled LDS (R1-verified code)
//  - B (Wp) and We read as direct global gathers (R6-prep-verified pattern)
//  - inj slice via E-staging + MFMA (R6-verified), bounced through wave-private
//    LDS into the jf fragment layout (R8-verified), rc folded into mask frag.
// ONE __syncthreads; no inter-block dependency; no workspace.
__global__ __launch_bounds__(256)
void fused_all(const float* __restrict__ patches,
               const float* __restrict__ embs,
               const int* __restrict__ locations,
               const float* __restrict__ Wp,
               const float* __restrict__ We,
               float* __restrict__ out) {
    __shared__ __align__(16) unsigned short Ash[64 * 256];    // 32 KB, swizzled
    __shared__ __align__(16) unsigned short Ebf[16 * 256];    // 8 KB, swizzled
    __shared__ __align__(16) unsigned short injW[4 * 16 * 32];// 4 KB, [wave][col][n]
    __shared__ unsigned maskL[64];
    __shared__ float rcL[64];

    const int bid = blockIdx.x, t = threadIdx.x;
    const int b = bid >> 6, pt = (bid >> 2) & 15, ct = bid & 3;
    const int p0 = pt * 64, c0 = ct * 64;
    const int wv = t >> 6, lane = t & 63, lhi = lane >> 4, llo = lane & 15;
    const int oc = c0 + wv * 16 + llo;   // output column this lane owns

    // ---- A staging: patches[b, p0..p0+64, :] -> bf16 LDS, XOR-swizzled rows ----
    const float* pbase = patches + (size_t)(b * 1024 + p0) * 256;
    #pragma unroll
    for (int it = 0; it < 16; ++it) {
        int u = t + it * 256;
        int row = u >> 6, c4 = u & 63;
        float4 f = *reinterpret_cast<const float4*>(pbase + row * 256 + c4 * 4);
        ushort4 o;
        o.x = f2bf(f.x); o.y = f2bf(f.y); o.z = f2bf(f.z); o.w = f2bf(f.w);
        int byte = row * 512 + ((c4 * 8) ^ ((row & 7) << 4));
        *reinterpret_cast<ushort4*>(reinterpret_cast<char*>(Ash) + byte) = o;
    }

    // ---- E staging: embs rows 0..14 (bf16, swizzled) + f32-accurate mean row 15 ----
    if (t < 128) {
        const int c0e = t * 2;
        float s0 = 0.f, s1 = 0.f;
        #pragma unroll
        for (int r = 0; r < 15; ++r) {
            float2 v = *reinterpret_cast<const float2*>(embs + (size_t)(b * 15 + r) * 256 + c0e);
            s0 += v.x; s1 += v.y;
            unsigned pk = (unsigned)f2bf(v.x) | ((unsigned)f2bf(v.y) << 16);
            *reinterpret_cast<unsigned*>(reinterpret_cast<char*>(Ebf)
                + r * 512 + ((c0e * 2) ^ ((r & 7) << 4))) = pk;
        }
        unsigned pk = (unsigned)f2bf(s0 * (1.0f / 15.0f))
                    | ((unsigned)f2bf(s1 * (1.0f / 15.0f)) << 16);
        *reinterpret_cast<unsigned*>(reinterpret_cast<char*>(Ebf)
            + 15 * 512 + ((c0e * 2) ^ (7 << 4))) = pk;
    }

    // ---- masks + 1/cnt for the 64 pixels ----
    if (t < 64) {
        int p = p0 + t;
        int h = p >> 5, w = p & 31;
        const int* loc = locations + b * 60;
        unsigned m = 1u << 15;  // full-image box always contains
        #pragma unroll
        for (int nb = 0; nb < 15; ++nb) {
            int y0 = loc[nb * 4 + 0] & ~1;
            int x0 = loc[nb * 4 + 1] & ~1;
            int y1 = (loc[nb * 4 + 2] & ~1) + 2;
            int x1 = (loc[nb * 4 + 3] & ~1) + 2;
            if (h >= y0 && h < y1 && w >= x0 && w < x1) m |= 1u << nb;
        }
        maskL[t] = m;
        rcL[t] = 1.0f / (float)__popc(m);
    }
    __syncthreads();   // the ONLY block barrier

    // ---- inj slice: (E_ext @ We)[:, oc] via MFMA (wave-private) ----
    f32x4 accI = (f32x4){0.f, 0.f, 0.f, 0.f};
    #pragma unroll
    for (int ks = 0; ks < 8; ++ks) {
        const short8 afr = *reinterpret_cast<const short8*>(
            reinterpret_cast<const char*>(Ebf)
            + llo * 512 + ((ks * 64 + lhi * 16) ^ ((llo & 7) << 4)));
        short8 bfr;
        #pragma unroll
        for (int r = 0; r < 8; ++r)
            bfr[r] = (short)f2bf(We[(size_t)(ks * 32 + lhi * 8 + r) * 256 + oc]);
        accI = __builtin_amdgcn_mfma_f32_16x16x32_bf16(afr, bfr, accI, 0, 0, 0);
    }
    // bounce to [col][n] bf16 (+ zero-pad n=16..31) -> jf fragment
    {
        ushort4 o4;
        o4.x = f2bf(accI[0]); o4.y = f2bf(accI[1]);
        o4.z = f2bf(accI[2]); o4.w = f2bf(accI[3]);
        unsigned short* dst = injW + wv * 512 + llo * 32;
        *reinterpret_cast<ushort4*>(dst + lhi * 4) = o4;
        ushort4 z = {0, 0, 0, 0};
        *reinterpret_cast<ushort4*>(dst + 16 + lhi * 4) = z;
    }
    asm volatile("s_waitcnt lgkmcnt(0)" ::: "memory");
    __builtin_amdgcn_sched_barrier(0);
    const short8 jf = *reinterpret_cast<const short8*>(injW + wv * 512 + llo * 32 + lhi * 8);

    // ---- main GEMM: 4 pixel-groups x 8 k-steps; B gathered from Wp (L2) ----
    f32x4 acc[4];
    #pragma unroll
    for (int mt = 0; mt < 4; ++mt) acc[mt] = (f32x4){0.f, 0.f, 0.f, 0.f};
    #pragma unroll
    for (int ks = 0; ks < 8; ++ks) {
        short8 bfr;
        #pragma unroll
        for (int r = 0; r < 8; ++r)
            bfr[r] = (short)f2bf(Wp[(size_t)(ks * 32 + lhi * 8 + r) * 256 + oc]);
        #pragma unroll
        for (int mt = 0; mt < 4; ++mt) {
            int row = mt * 16 + llo;
            const short8 af = *reinterpret_cast<const short8*>(
                reinterpret_cast<const char*>(Ash)
                + row * 512 + (((ks * 32 + lhi * 8) * 2) ^ ((row & 7) << 4)));
            acc[mt] = __builtin_amdgcn_mfma_f32_16x16x32_bf16(af, bfr, acc[mt], 0, 0, 0);
        }
    }

    // ---- epilogue: rc-folded mask MFMA per pixel-group, then store ----
    #pragma unroll
    for (int mt = 0; mt < 4; ++mt) {
        unsigned m = maskL[mt * 16 + llo];
        unsigned short rcb = f2bf(rcL[mt * 16 + llo]);
        short8 mfrag;
        #pragma unroll
        for (int r = 0; r < 8; ++r) {
            int k = lhi * 8 + r;
            mfrag[r] = (k < 16 && ((m >> k) & 1u)) ? (short)rcb : (short)0;
        }
        f32x4 accE = __builtin_amdgcn_mfma_f32_16x16x32_bf16(
            mfrag, jf, (f32x4){0.f, 0.f, 0.f, 0.f}, 0, 0, 0);
        float* ob = out + (size_t)(b * 1024 + p0 + mt * 16) * 256;
        #pragma unroll
        for (int j = 0; j < 4; ++j)
            ob[(lhi * 4 + j) * 256 + oc] = acc[mt][j] + accE[j];
    }
}

extern "C" void kernel_launch(void* const* d_in, const int* in_sizes, int n_in,
                              void* d_out, int out_size, void* d_ws, size_t ws_size,
                              hipStream_t stream) {
    const float* patches = (const float*)d_in[0];
    const float* embs    = (const float*)d_in[1];
    const int*   locs    = (const int*)d_in[2];
    const float* Wp      = (const float*)d_in[3];
    const float* We      = (const float*)d_in[4];
    float* out = (float*)d_out;

    fused_all<<<512, 256, 0, stream>>>(patches, embs, locs, Wp, We, out);
}